// Round 2
// baseline (225.996 us; speedup 1.0000x reference)
//
#include <hip/hip_runtime.h>

#define BATCH 16
#define CH    64
#define TLEN  200
#define NP    30
#define HID   128
#define NSEQ  (BATCH * NP)   // 480
#define HXP   136            // h row pitch: 128 + 8 pad halves (272 B = 17 quads -> balanced banks)
#define XBP   72             // x row pitch: 64 + 8 pad halves (144 B = 9 quads -> balanced banks)

typedef _Float16 half8  __attribute__((ext_vector_type(8)));
typedef _Float16 half2v __attribute__((ext_vector_type(2)));
typedef float    f32x4  __attribute__((ext_vector_type(4)));

__device__ __forceinline__ float sigm_fast(float x) {
    return __builtin_amdgcn_rcpf(1.0f + __expf(-x));
}
__device__ __forceinline__ float tanh_fast(float x) {
    float xc = fminf(15.0f, fmaxf(-15.0f, x));
    float e = __expf(2.0f * xc);
    return (e - 1.0f) * __builtin_amdgcn_rcpf(e + 1.0f);
}
__device__ __forceinline__ half8 cvt8(float4 a, float4 b) {
    return (half8){(_Float16)a.x,(_Float16)a.y,(_Float16)a.z,(_Float16)a.w,
                   (_Float16)b.x,(_Float16)b.y,(_Float16)b.z,(_Float16)b.w};
}

#define MFMA16(A,B,C) __builtin_amdgcn_mfma_f32_16x16x32_f16((A),(B),(C),0,0,0)

// ---------------------------------------------------------------------------
// One fused kernel. Block = 2 sequences (240 blocks ~ 1/CU), 8 waves.
// Recurrent step: gates = h_t (K=128) @ W_hh^T via 16 MFMAs/wave, with the
// x @ W_ih^T contribution precomputed one 8-step period ahead:
//   - every period (8 steps), one K=64 GEMM over a 16-row x-tile (8 steps x
//     2 seqs) produces xg(+bias) for the NEXT period; its 8 MFMAs are
//     interleaved 1/step so they execute in the activation/barrier shadow.
//   - activation lanes (l<16) read their 8 xg values (2 seqs x i,f,g,o) with
//     one conflict-free ds_read_b128; no shfl anywhere (lanes 0-15 own both
//     seq rows of the C fragment directly: row = (l>>4)*4 + reg).
//   - x is staged 2 periods ahead (1 load/loader-lane/step, depth-1 reg
//     pipeline) -> HBM latency fully hidden.
// ---------------------------------------------------------------------------
__global__ __launch_bounds__(512) void fused_lstm(
    const float* __restrict__ x, const float* __restrict__ W_ih,
    const float* __restrict__ W_hh, const float* __restrict__ b_ih,
    const float* __restrict__ b_hh, const float* __restrict__ W_fc,
    const float* __restrict__ b_fc, float* __restrict__ out)
{
    const int tid = threadIdx.x;
    const int w  = tid >> 6;     // wave 0..7 -> owns hid [16w,16w+16)
    const int l  = tid & 63;
    const int lr = l & 15;
    const int lq = l >> 4;

    const int n0 = blockIdx.x * 2;
    const int b0 = n0 / NP;
    const int p0 = n0 % NP;      // even -> both seqs share b0

    __shared__ __align__(16) _Float16 hx2[2][16][HXP];       // h double-buffer (rows 2-15 stay 0)
    __shared__ __align__(16) _Float16 xbuf[2][16][XBP];      // x tiles, row = 2*delta + s
    __shared__ __align__(16) _Float16 xgb[2][8][HID][8];     // xg+bias: [buf][delta][hid][s*4+{i,f,g,o}]

    // ---- W fragments in registers (loaded once) ----
    half8 bhh[4][4];   // W_hh, gate-type T, K-frag kt (K=128)
    half8 bih[4][2];   // W_ih, gate-type T, K-frag j  (K=64)
#pragma unroll
    for (int T = 0; T < 4; ++T) {
        const int g = 128*T + 16*w + lr;
        const float* rh = W_hh + (size_t)g * HID;
        const float* ri = W_ih + (size_t)g * CH;
#pragma unroll
        for (int kt = 0; kt < 4; ++kt) {
            const int k0 = 32*kt + 8*lq;
            bhh[T][kt] = cvt8(*(const float4*)(rh + k0), *(const float4*)(rh + k0 + 4));
        }
#pragma unroll
        for (int j = 0; j < 2; ++j) {
            const int k0 = 32*j + 8*lq;
            bih[T][j] = cvt8(*(const float4*)(ri + k0), *(const float4*)(ri + k0 + 4));
        }
    }
    float bias0, bias1, bias2, bias3;
    {
        const int gb = 16*w + lr;
        bias0 = b_ih[gb]       + b_hh[gb];
        bias1 = b_ih[gb + 128] + b_hh[gb + 128];
        bias2 = b_ih[gb + 256] + b_hh[gb + 256];
        bias3 = b_ih[gb + 384] + b_hh[gb + 384];
    }

    // zero hx2 (rows 2-15 stay zero forever; rows 0,1 = h_0 = 0)
    for (int i = tid; i < (2*16*HXP)/2; i += 512) ((unsigned*)hx2)[i] = 0u;

    // ---- x loaders: lanes 16..31 of each wave = 128 threads, one (s,ch) each
    const bool isload = (l >= 16 && l < 32);
    int ls = 0, lc = 0;
    const float* xbase = nullptr;
    float xpend = 0.f;
    f32x4 xga0, xga1, xga2, xga3;
    half8 xf0, xf1;
    if (isload) {
        const int idx = w * 16 + (l - 16);
        ls = idx >> 6;                    // seq 0/1
        lc = idx & 63;                    // channel
        xbase = x + ((size_t)(b0 * CH + lc) * TLEN) * NP + p0 + ls;
        // prologue staging: periods 0 and 1 (u = global t = 0..15)
#pragma unroll
        for (int u = 0; u < 16; ++u)
            xbuf[u >> 3][2*(u & 7) + ls][lc] = (_Float16)xbase[(size_t)u * NP];
        xpend = xbase[(size_t)16 * NP];   // preload u=16 (written at t=0)
    }
    float c0 = 0.f, c1 = 0.f;            // c-state in lanes l<16: c[s][hid=16w+lr]
    __syncthreads();                      // hx2 zeroed + xbuf[0],xbuf[1] staged

#define WRITE_XGA(BUF) {                                                          \
        _Float16* q0_ = &xgb[BUF][2*lq][16*w + lr][0];                            \
        _Float16* q1_ = &xgb[BUF][2*lq + 1][16*w + lr][0];                        \
        *(half2v*)(q0_ + 0) = (half2v){(_Float16)xga0[0], (_Float16)xga1[0]};     \
        *(half2v*)(q0_ + 2) = (half2v){(_Float16)xga2[0], (_Float16)xga3[0]};     \
        *(half2v*)(q0_ + 4) = (half2v){(_Float16)xga0[1], (_Float16)xga1[1]};     \
        *(half2v*)(q0_ + 6) = (half2v){(_Float16)xga2[1], (_Float16)xga3[1]};     \
        *(half2v*)(q1_ + 0) = (half2v){(_Float16)xga0[2], (_Float16)xga1[2]};     \
        *(half2v*)(q1_ + 2) = (half2v){(_Float16)xga2[2], (_Float16)xga3[2]};     \
        *(half2v*)(q1_ + 4) = (half2v){(_Float16)xga0[3], (_Float16)xga1[3]};     \
        *(half2v*)(q1_ + 6) = (half2v){(_Float16)xga2[3], (_Float16)xga3[3]}; }

    // ---- prologue xg-GEMM (for period 0) from xbuf[0] -> xgb[0]
    {
        const _Float16* xr = &xbuf[0][lr][8 * lq];
        xf0 = *(const half8*)xr;
        xf1 = *(const half8*)(xr + 32);
        xga0 = (f32x4){bias0, bias0, bias0, bias0};
        xga1 = (f32x4){bias1, bias1, bias1, bias1};
        xga2 = (f32x4){bias2, bias2, bias2, bias2};
        xga3 = (f32x4){bias3, bias3, bias3, bias3};
        xga0 = MFMA16(xf0, bih[0][0], xga0); xga0 = MFMA16(xf1, bih[0][1], xga0);
        xga1 = MFMA16(xf0, bih[1][0], xga1); xga1 = MFMA16(xf1, bih[1][1], xga1);
        xga2 = MFMA16(xf0, bih[2][0], xga2); xga2 = MFMA16(xf1, bih[2][1], xga2);
        xga3 = MFMA16(xf0, bih[3][0], xga3); xga3 = MFMA16(xf1, bih[3][1], xga3);
        WRITE_XGA(0)
    }
    __syncthreads();

#define MM4(A, KT)                                                       \
        ci = MFMA16(A, bhh[0][KT], ci); cf = MFMA16(A, bhh[1][KT], cf);  \
        cg = MFMA16(A, bhh[2][KT], cg); co = MFMA16(A, bhh[3][KT], co);

#pragma unroll 1
    for (int p = 0; p < 25; ++p) {
        const int pe = p & 1;            // xgb consume buf; xbuf staging dest = (p+2)&1 = pe
#pragma unroll
        for (int k = 0; k < 8; ++k) {
            const int cur = k & 1;       // t = 8p+k, t&1 = k&1
            const int nxt = cur ^ 1;
            if (k == 0) {                // load next period's x-tile frags, init xg accs
                const _Float16* xr = &xbuf[pe ^ 1][lr][8 * lq];
                xf0 = *(const half8*)xr;
                xf1 = *(const half8*)(xr + 32);
                xga0 = (f32x4){bias0, bias0, bias0, bias0};
                xga1 = (f32x4){bias1, bias1, bias1, bias1};
                xga2 = (f32x4){bias2, bias2, bias2, bias2};
                xga3 = (f32x4){bias3, bias3, bias3, bias3};
            }
            // A fragments (h only, K=128); rows 2-15 are zero -> C rows 2-15 garbage-ok
            const _Float16* hr = &hx2[cur][lr][8 * lq];
            half8 a0 = *(const half8*)(hr);
            half8 a1 = *(const half8*)(hr + 32);
            half8 a2 = *(const half8*)(hr + 64);
            half8 a3 = *(const half8*)(hr + 96);
            f32x4 ci = {0.f, 0.f, 0.f, 0.f};
            f32x4 cf = ci, cg = ci, co = ci;
            MM4(a0, 0) MM4(a1, 1) MM4(a2, 2) MM4(a3, 3)
            // interleaved lookahead xg-MFMA (1/step; executes in the tail shadow)
            if (k == 0) xga0 = MFMA16(xf0, bih[0][0], xga0);
            if (k == 1) xga0 = MFMA16(xf1, bih[0][1], xga0);
            if (k == 2) xga1 = MFMA16(xf0, bih[1][0], xga1);
            if (k == 3) xga1 = MFMA16(xf1, bih[1][1], xga1);
            if (k == 4) xga2 = MFMA16(xf0, bih[2][0], xga2);
            if (k == 5) xga2 = MFMA16(xf1, bih[2][1], xga2);
            if (k == 6) xga3 = MFMA16(xf0, bih[3][0], xga3);
            if (k == 7) xga3 = MFMA16(xf1, bih[3][1], xga3);

            if (l < 16) {
                // 16-lane b128 read, stride 16 B -> conflict-free
                half8 xgv = *(const half8*)&xgb[pe][k][16*w + lr][0];
                float gi0 = ci[0] + (float)xgv[0];
                float gf0 = cf[0] + (float)xgv[1];
                float gg0 = cg[0] + (float)xgv[2];
                float go0 = co[0] + (float)xgv[3];
                float gi1 = ci[1] + (float)xgv[4];
                float gf1 = cf[1] + (float)xgv[5];
                float gg1 = cg[1] + (float)xgv[6];
                float go1 = co[1] + (float)xgv[7];
                c0 = sigm_fast(gf0) * c0 + sigm_fast(gi0) * tanh_fast(gg0);
                c1 = sigm_fast(gf1) * c1 + sigm_fast(gi1) * tanh_fast(gg1);
                hx2[nxt][0][16*w + lr] = (_Float16)(sigm_fast(go0) * tanh_fast(c0));
                hx2[nxt][1][16*w + lr] = (_Float16)(sigm_fast(go1) * tanh_fast(c1));
            } else if (l < 32) {
                // stage x for period p+2: u = t+16 -> row 2k+s of xbuf[pe]
                xbuf[pe][2*k + ls][lc] = (_Float16)xpend;
                int tq = 8*p + k + 17;             // next load, 2 periods ahead
                tq = tq > TLEN - 1 ? TLEN - 1 : tq;
                xpend = xbase[(size_t)tq * NP];
            }
            if (k == 7) WRITE_XGA(pe ^ 1)          // xg for period p+1
            __syncthreads();
        }
    }

    // FC epilogue: h_200 sits in hx2[0] rows 0,1 (t=199 wrote nxt=0)
    if (tid < 2 * CH) {
        const int s = tid >> 6, ch = tid & 63;
        const float* wf = W_fc + (size_t)ch * HID;
        float acc = b_fc[ch];
#pragma unroll
        for (int j8 = 0; j8 < 16; ++j8) {
            half8 hv = *(const half8*)&hx2[0][s][8 * j8];
            float4 w0 = *(const float4*)(wf + 8 * j8);
            float4 w1 = *(const float4*)(wf + 8 * j8 + 4);
            acc += w0.x * (float)hv[0] + w0.y * (float)hv[1]
                 + w0.z * (float)hv[2] + w0.w * (float)hv[3]
                 + w1.x * (float)hv[4] + w1.y * (float)hv[5]
                 + w1.z * (float)hv[6] + w1.w * (float)hv[7];
        }
        out[(size_t)(n0 + s) * CH + ch] = acc;
    }
}

extern "C" void kernel_launch(void* const* d_in, const int* in_sizes, int n_in,
                              void* d_out, int out_size, void* d_ws, size_t ws_size,
                              hipStream_t stream) {
    (void)in_sizes; (void)n_in; (void)out_size; (void)d_ws; (void)ws_size;
    fused_lstm<<<NSEQ / 2, 512, 0, stream>>>(
        (const float*)d_in[0], (const float*)d_in[1], (const float*)d_in[2],
        (const float*)d_in[3], (const float*)d_in[4], (const float*)d_in[5],
        (const float*)d_in[6], (float*)d_out);
}

// Round 3
// 195.714 us; speedup vs baseline: 1.1547x; 1.1547x over previous
//
#include <hip/hip_runtime.h>

#define BATCH 16
#define CH    64
#define TLEN  200
#define NP    30
#define HID   128
#define NSEQ  (BATCH * NP)   // 480
#define HXP   136            // h row pitch in halves (272 B -> 2-way max bank aliasing)
#define XBP   72             // x-tile row pitch in halves

typedef _Float16 half8  __attribute__((ext_vector_type(8)));
typedef _Float16 half4v __attribute__((ext_vector_type(4)));
typedef float    f32x4  __attribute__((ext_vector_type(4)));

__device__ __forceinline__ float sigm_fast(float x) {
    return __builtin_amdgcn_rcpf(1.0f + __expf(-x));
}
__device__ __forceinline__ float tanh_fast(float x) {
    float xc = fminf(15.0f, fmaxf(-15.0f, x));
    float e = __expf(2.0f * xc);
    return (e - 1.0f) * __builtin_amdgcn_rcpf(e + 1.0f);
}
__device__ __forceinline__ half8 cvt8(float4 a, float4 b) {
    return (half8){(_Float16)a.x,(_Float16)a.y,(_Float16)a.z,(_Float16)a.w,
                   (_Float16)b.x,(_Float16)b.y,(_Float16)b.z,(_Float16)b.w};
}

#define MFMA16(A,B,C) __builtin_amdgcn_mfma_f32_16x16x32_f16((A),(B),(C),0,0,0)

// ---------------------------------------------------------------------------
// Fused LSTM, S=2 seqs/block, 240 blocks, 8 waves. Recurrent K=128 (16
// MFMAs/wave/step); x@W_ih precomputed per 8-step period in a single compact
// burst at k==0 (8 MFMAs + 2 LDS writes, amortized ~1/8 per step).
//   - h rows replicated {s, s+4} in the A-tile so lanes 16-31 hold seq1's
//     gates in their own C reg 1: activation = 32 lanes, 1 cell/lane, zero
//     cross-lane ops (4 v_cndmask selects replace round-1's 4 shfl_up).
//   - xg values (b64/lane, conflict-free) prefetched at the TOP of the step
//     so the LDS latency hides under the MFMA issue window.
//   - x staged 2 periods ahead by lanes 32..47 (1 load + 1 LDS write/step).
// ---------------------------------------------------------------------------
__global__ __launch_bounds__(512) void fused_lstm(
    const float* __restrict__ x, const float* __restrict__ W_ih,
    const float* __restrict__ W_hh, const float* __restrict__ b_ih,
    const float* __restrict__ b_hh, const float* __restrict__ W_fc,
    const float* __restrict__ b_fc, float* __restrict__ out)
{
    const int tid = threadIdx.x;
    const int w  = tid >> 6;     // wave 0..7 -> owns hid [16w,16w+16)
    const int l  = tid & 63;
    const int lr = l & 15;
    const int lq = l >> 4;

    const int n0 = blockIdx.x * 2;
    const int b0 = n0 / NP;
    const int p0 = n0 % NP;      // even -> both seqs share b0

    __shared__ __align__(16) _Float16 hx2[2][16][HXP];   // h, rows {0,1,4,5} live, rest 0
    __shared__ __align__(16) _Float16 xbuf[2][16][XBP];  // x tiles, row = 2*delta + s
    __shared__ __align__(16) _Float16 xgb[2][8][HID][8]; // xg+bias: [buf][delta][hid][s*4+{i,f,g,o}]

    // ---- W fragments in registers (loaded once) ----
    half8 bhh[4][4];   // W_hh, gate-type T, K-frag kt (K=128)
    half8 bih[4][2];   // W_ih, gate-type T, K-frag j  (K=64)
#pragma unroll
    for (int T = 0; T < 4; ++T) {
        const int g = 128*T + 16*w + lr;
        const float* rh = W_hh + (size_t)g * HID;
        const float* ri = W_ih + (size_t)g * CH;
#pragma unroll
        for (int kt = 0; kt < 4; ++kt) {
            const int k0 = 32*kt + 8*lq;
            bhh[T][kt] = cvt8(*(const float4*)(rh + k0), *(const float4*)(rh + k0 + 4));
        }
#pragma unroll
        for (int j = 0; j < 2; ++j) {
            const int k0 = 32*j + 8*lq;
            bih[T][j] = cvt8(*(const float4*)(ri + k0), *(const float4*)(ri + k0 + 4));
        }
    }
    float bias0, bias1, bias2, bias3;
    {
        const int gb = 16*w + lr;
        bias0 = b_ih[gb]       + b_hh[gb];
        bias1 = b_ih[gb + 128] + b_hh[gb + 128];
        bias2 = b_ih[gb + 256] + b_hh[gb + 256];
        bias3 = b_ih[gb + 384] + b_hh[gb + 384];
    }

    // zero hx2 (rows 2,3,6,7,8-15 stay zero forever; rows 0,1,4,5 = h_0 = 0)
    for (int i = tid; i < (2*16*HXP)/2; i += 512) ((unsigned*)hx2)[i] = 0u;

    // ---- x loaders: lanes 32..47 of each wave = 128 threads, one (s,ch) each
    const bool isload = (l >= 32 && l < 48);
    int ls = 0, lc = 0;
    const float* xbase = nullptr;
    float xpend = 0.f;
    if (isload) {
        const int idx = w * 16 + (l - 32);
        ls = idx >> 6;                    // seq 0/1
        lc = idx & 63;                    // channel
        xbase = x + ((size_t)(b0 * CH + lc) * TLEN) * NP + p0 + ls;
        // prologue staging: periods 0 and 1 (u = global t = 0..15)
#pragma unroll
        for (int u = 0; u < 16; ++u)
            xbuf[u >> 3][2*(u & 7) + ls][lc] = (_Float16)xbase[(size_t)u * NP];
        xpend = xbase[(size_t)16 * NP];   // preload t=16 (staged at t=0)
    }
    float cst = 0.f;   // c-state: lanes l<32 hold c[seq=l>>4][hid=16w+lr]
    const int hcol = 16*w + lr;
    const int sq = lq & 1;               // xg seq slot for this lane
    __syncthreads();                      // hx2 zeroed + xbuf[0],xbuf[1] staged

    // compact per-period xg GEMM: x-tile (16 rows = 8 steps x 2 seqs, K=64)
    // C row (lq*4+r) = x-row 2*delta+s -> delta = 2lq + (r>>1), s = r&1.
#define XG_BURST(SB, TB) {                                                        \
        const _Float16* xr_ = &xbuf[SB][lr][8*lq];                                \
        half8 xf0_ = *(const half8*)xr_;                                          \
        half8 xf1_ = *(const half8*)(xr_ + 32);                                   \
        f32x4 x0_ = {bias0, bias0, bias0, bias0};                                 \
        f32x4 x1_ = {bias1, bias1, bias1, bias1};                                 \
        f32x4 x2_ = {bias2, bias2, bias2, bias2};                                 \
        f32x4 x3_ = {bias3, bias3, bias3, bias3};                                 \
        x0_ = MFMA16(xf0_, bih[0][0], x0_); x0_ = MFMA16(xf1_, bih[0][1], x0_);   \
        x1_ = MFMA16(xf0_, bih[1][0], x1_); x1_ = MFMA16(xf1_, bih[1][1], x1_);   \
        x2_ = MFMA16(xf0_, bih[2][0], x2_); x2_ = MFMA16(xf1_, bih[2][1], x2_);   \
        x3_ = MFMA16(xf0_, bih[3][0], x3_); x3_ = MFMA16(xf1_, bih[3][1], x3_);   \
        half8 r0_ = {(_Float16)x0_[0],(_Float16)x1_[0],(_Float16)x2_[0],(_Float16)x3_[0],  \
                     (_Float16)x0_[1],(_Float16)x1_[1],(_Float16)x2_[1],(_Float16)x3_[1]}; \
        half8 r1_ = {(_Float16)x0_[2],(_Float16)x1_[2],(_Float16)x2_[2],(_Float16)x3_[2],  \
                     (_Float16)x0_[3],(_Float16)x1_[3],(_Float16)x2_[3],(_Float16)x3_[3]}; \
        *(half8*)&xgb[TB][2*lq][hcol][0]     = r0_;                               \
        *(half8*)&xgb[TB][2*lq + 1][hcol][0] = r1_; }

    XG_BURST(0, 0)          // xg for period 0
    __syncthreads();

#define MM4(A, KT)                                                       \
        ci = MFMA16(A, bhh[0][KT], ci); cf = MFMA16(A, bhh[1][KT], cf);  \
        cg = MFMA16(A, bhh[2][KT], cg); co = MFMA16(A, bhh[3][KT], co);

#pragma unroll 1
    for (int p = 0; p < 25; ++p) {
        const int pe = p & 1;
#pragma unroll
        for (int k = 0; k < 8; ++k) {
            const int cur = k & 1;       // t = 8p+k, t&1 = k&1
            const int nxt = cur ^ 1;
            // xg prefetch first: b64, conflict-free; latency hides under MFMAs
            half4v xgv = *(const half4v*)&xgb[pe][k][hcol][4*sq];
            // A fragments (h only, K=128); zero rows make C rows 2,3,6,7.. dead
            const _Float16* hr = &hx2[cur][lr][8*lq];
            half8 a0 = *(const half8*)(hr);
            half8 a1 = *(const half8*)(hr + 32);
            half8 a2 = *(const half8*)(hr + 64);
            half8 a3 = *(const half8*)(hr + 96);
            f32x4 ci = {0.f, 0.f, 0.f, 0.f};
            f32x4 cf = ci, cg = ci, co = ci;
            MM4(a0, 0) MM4(a1, 1) MM4(a2, 2) MM4(a3, 3)
            if (k == 0 && p < 24) XG_BURST(pe ^ 1, pe ^ 1)   // xg for period p+1
            if (l < 32) {
                // lanes 0-15: seq0 via reg0 (row 0); lanes 16-31: seq1 via reg1 (row 5 = replica)
                const bool lo = (l < 16);
                float gi = (lo ? ci[0] : ci[1]) + (float)xgv[0];
                float gf = (lo ? cf[0] : cf[1]) + (float)xgv[1];
                float gg = (lo ? cg[0] : cg[1]) + (float)xgv[2];
                float go = (lo ? co[0] : co[1]) + (float)xgv[3];
                cst = sigm_fast(gf) * cst + sigm_fast(gi) * tanh_fast(gg);
                float hv = sigm_fast(go) * tanh_fast(cst);
                _Float16 hh = (_Float16)hv;
                const int s_ = l >> 4;
                hx2[nxt][s_][hcol]     = hh;     // primary row
                hx2[nxt][s_ + 4][hcol] = hh;     // replica row (feeds lanes 16-31's regs)
            } else if (isload) {
                // stage x for period p+2: t = 8p+k+16 -> row 2k+s of xbuf[pe]
                xbuf[pe][2*k + ls][lc] = (_Float16)xpend;
                int tq = 8*p + k + 17;
                tq = tq > TLEN - 1 ? TLEN - 1 : tq;
                xpend = xbase[(size_t)tq * NP];
            }
            __syncthreads();
        }
    }

    // FC epilogue: h_200 sits in hx2[0] rows 0,1 (t=199 wrote nxt=0)
    if (tid < 2 * CH) {
        const int s = tid >> 6, ch = tid & 63;
        const float* wf = W_fc + (size_t)ch * HID;
        float acc = b_fc[ch];
#pragma unroll
        for (int j8 = 0; j8 < 16; ++j8) {
            half8 hv = *(const half8*)&hx2[0][s][8 * j8];
            float4 w0 = *(const float4*)(wf + 8 * j8);
            float4 w1 = *(const float4*)(wf + 8 * j8 + 4);
            acc += w0.x * (float)hv[0] + w0.y * (float)hv[1]
                 + w0.z * (float)hv[2] + w0.w * (float)hv[3]
                 + w1.x * (float)hv[4] + w1.y * (float)hv[5]
                 + w1.z * (float)hv[6] + w1.w * (float)hv[7];
        }
        out[(size_t)(n0 + s) * CH + ch] = acc;
    }
}

extern "C" void kernel_launch(void* const* d_in, const int* in_sizes, int n_in,
                              void* d_out, int out_size, void* d_ws, size_t ws_size,
                              hipStream_t stream) {
    (void)in_sizes; (void)n_in; (void)out_size; (void)d_ws; (void)ws_size;
    fused_lstm<<<NSEQ / 2, 512, 0, stream>>>(
        (const float*)d_in[0], (const float*)d_in[1], (const float*)d_in[2],
        (const float*)d_in[3], (const float*)d_in[4], (const float*)d_in[5],
        (const float*)d_in[6], (float*)d_out);
}